// Round 1
// baseline (498.785 us; speedup 1.0000x reference)
//
#include <hip/hip_runtime.h>
#include <stdint.h>
#include <stddef.h>

// IMEC classifier: 10000 tiny MLPs (1024->8->1) over 256 embeddings.
//   logits[b,l] = sum_d relu( sum_h E[b,h]*W1[l,h,d] + b1[l,d] ) * W2[l,d] + b2[l]
// Strategy: bf16 MFMA (16x16x32), HBM-bound on the 328 MB W1 stream.
//   - prep kernel: E fp32 -> bf16 into d_ws, tiled+swizzled for global_load_lds
//   - main kernel: WG=256 thr, 8 labels, full 256-row batch; 2-barrier K-loop,
//     W1 global->reg->cvt->LDS (MFMA-lane order), E via global_load_lds(16B).

#define B_ 256
#define H_ 1024
#define L_ 10000
#define D_ 8
#define NL 8            // labels per workgroup
#define KB 32           // K elements per step
#define NSTEP (H_ / KB) // 32

typedef __bf16 bf16_t;
typedef bf16_t bf16x8 __attribute__((ext_vector_type(8)));
typedef float f32x4 __attribute__((ext_vector_type(4)));
typedef int i32x4 __attribute__((ext_vector_type(4)));

// round-to-nearest-even fp32 -> bf16, pack two into one dword
__device__ __forceinline__ uint32_t cvt_pk_bf16(float lo, float hi) {
  uint32_t a = __builtin_bit_cast(uint32_t, lo);
  uint32_t b = __builtin_bit_cast(uint32_t, hi);
  a += 0x7FFFu + ((a >> 16) & 1u);
  b += 0x7FFFu + ((b >> 16) & 1u);
  return (a >> 16) | (b & 0xFFFF0000u);
}

__device__ __forceinline__ void gl_lds16(const void* g, void* l) {
  __builtin_amdgcn_global_load_lds(
      (const __attribute__((address_space(1))) uint32_t*)g,
      (__attribute__((address_space(3))) uint32_t*)l, 16, 0, 0);
}

// Prep: E[256,1024] fp32 -> bf16 in d_ws, layout [kb=0..63? no: H/KB=32][m=0..255][chunk 0..3][8 bf16]
// chunk swizzle: original chunk c stored at position c ^ ((m>>1)&3)  (A-read bank spread)
__global__ void imec_prep(const float* __restrict__ E, uint8_t* __restrict__ Ebf) {
  const int t = blockIdx.x * blockDim.x + threadIdx.x; // 0..32767
  const int m = t >> 7;       // row 0..255
  const int cg = t & 127;     // chunk-in-row 0..127
  const int kb = cg >> 2;     // k-step 0..31
  const int c = cg & 3;       // chunk within k-step
  const float* src = E + (size_t)m * H_ + kb * KB + c * 8;
  f32x4 x = *(const f32x4*)src;
  f32x4 y = *(const f32x4*)(src + 4);
  i32x4 v;
  v[0] = cvt_pk_bf16(x[0], x[1]);
  v[1] = cvt_pk_bf16(x[2], x[3]);
  v[2] = cvt_pk_bf16(y[0], y[1]);
  v[3] = cvt_pk_bf16(y[2], y[3]);
  const int cp = c ^ ((m >> 1) & 3);
  *(i32x4*)(Ebf + ((size_t)kb << 14) + (m << 6) + (cp << 4)) = v;
}

template <bool USE_WS>
__global__ __launch_bounds__(256, 2) void imec_main(
    const float* __restrict__ E, const float* __restrict__ W1,
    const float* __restrict__ b1, const float* __restrict__ W2,
    const float* __restrict__ b2, float* __restrict__ out,
    const uint8_t* __restrict__ Ebf) {
  // LDS: E tile [256 m][4 chunk][16B] = 16 KB ; W1 tile, MFMA-lane order:
  //      [pair 0..3][lane 0..63][16B] = 4 KB
  __shared__ alignas(16) uint8_t sE[16384];
  __shared__ alignas(16) uint8_t sW[4096];

  const int tid = threadIdx.x;
  const int w = tid >> 6;    // wave 0..3 (owns M rows [w*64, w*64+64), stages pair w)
  const int lane = tid & 63;
  const int wg = blockIdx.x; // labels [wg*8, wg*8+8)
  const int n = lane & 15;   // MFMA column / row-in-tile index
  const int q = lane >> 4;   // MFMA k-quad

  // --- W1 staging address for this lane (pair = w, its 16B B-frag chunk) ---
  const int d_st = n & 7;
  const int lp_st = n >> 3;
  const long label_st = (long)wg * NL + w * 2 + lp_st;
  const float* w1p = W1 + label_st * (long)(H_ * D_) + (q * 8) * D_ + d_st;

  f32x4 acc[4][4];
#pragma unroll
  for (int i = 0; i < 4; ++i)
#pragma unroll
    for (int j = 0; j < 4; ++j) acc[i][j] = (f32x4){0.f, 0.f, 0.f, 0.f};

  // prefetch k-step 0 W1 slab into regs
  float r[8];
#pragma unroll
  for (int j = 0; j < 8; ++j) r[j] = w1p[j * D_];
  w1p += KB * D_;

  const int sw = (n >> 1) & 3; // A-read chunk swizzle

  for (int kb = 0; kb < NSTEP; ++kb) {
    __syncthreads(); // (a) previous iteration's LDS reads done

    // ---- stage E tile ----
    if constexpr (USE_WS) {
#pragma unroll
      for (int i = 0; i < 4; ++i) {
        const uint8_t* g =
            Ebf + ((size_t)kb << 14) + (w << 12) + (i << 10) + (lane << 4);
        gl_lds16(g, sE + (w << 12) + (i << 10)); // HW: +lane*16
      }
    } else {
      const int m = tid;
      const f32x4* er = (const f32x4*)(E + (size_t)m * H_ + kb * KB);
#pragma unroll
      for (int c = 0; c < 4; ++c) {
        f32x4 x = er[2 * c];
        f32x4 y = er[2 * c + 1];
        i32x4 v;
        v[0] = cvt_pk_bf16(x[0], x[1]);
        v[1] = cvt_pk_bf16(x[2], x[3]);
        v[2] = cvt_pk_bf16(y[0], y[1]);
        v[3] = cvt_pk_bf16(y[2], y[3]);
        *(i32x4*)(sE + (m << 6) + ((c ^ ((m >> 1) & 3)) << 4)) = v;
      }
    }

    // ---- stage W1 tile: cvt prefetched regs -> bf16, lane-ordered LDS ----
    {
      i32x4 v;
      v[0] = cvt_pk_bf16(r[0], r[1]);
      v[1] = cvt_pk_bf16(r[2], r[3]);
      v[2] = cvt_pk_bf16(r[4], r[5]);
      v[3] = cvt_pk_bf16(r[6], r[7]);
      *(i32x4*)(sW + (w << 10) + (lane << 4)) = v;
    }
    __syncthreads(); // (b) tiles visible

    // ---- prefetch next W1 slab during compute phase (hides HBM latency
    //      behind MFMAs; drained at next barrier (a)) ----
    if (kb + 1 < NSTEP) {
#pragma unroll
      for (int j = 0; j < 8; ++j) r[j] = w1p[j * D_];
      w1p += KB * D_;
    }

    // ---- fragments ----
    bf16x8 bfr[4];
#pragma unroll
    for (int t = 0; t < 4; ++t)
      bfr[t] = *(const bf16x8*)(sW + (t << 10) + (lane << 4));
    bf16x8 afr[4];
#pragma unroll
    for (int mt = 0; mt < 4; ++mt) {
      const int ml = w * 64 + mt * 16 + n;
      afr[mt] = *(const bf16x8*)(sE + (ml << 6) + ((q ^ sw) << 4));
    }

#pragma unroll
    for (int mt = 0; mt < 4; ++mt)
#pragma unroll
      for (int t = 0; t < 4; ++t)
        acc[mt][t] = __builtin_amdgcn_mfma_f32_16x16x32_bf16(
            afr[mt], bfr[t], acc[mt][t], 0, 0, 0);
  }

  // ---- epilogue: h -> relu(h+b1)*W2 summed over d (8 lanes), +b2 ----
  // C/D layout: col = lane&15 -> (pair-local label = n>>3, d = n&7),
  //             row = q*4 + reg -> batch row within tile.
#pragma unroll
  for (int t = 0; t < 4; ++t) {
    const int label = wg * NL + t * 2 + lp_st;
    const float b1v = b1[label * D_ + d_st];
    const float w2v = W2[label * D_ + d_st];
    const float b2v = b2[label];
#pragma unroll
    for (int mt = 0; mt < 4; ++mt) {
#pragma unroll
      for (int rr = 0; rr < 4; ++rr) {
        float v = acc[mt][t][rr] + b1v;
        v = fmaxf(v, 0.f) * w2v;
        v += __shfl_xor(v, 1);
        v += __shfl_xor(v, 2);
        v += __shfl_xor(v, 4);
        if ((lane & 7) == 0) { // n == 0 or 8 -> d == 0 lane of each label
          const int m = w * 64 + mt * 16 + q * 4 + rr;
          out[(size_t)m * L_ + label] = v + b2v;
        }
      }
    }
  }
}

extern "C" void kernel_launch(void* const* d_in, const int* in_sizes, int n_in,
                              void* d_out, int out_size, void* d_ws,
                              size_t ws_size, hipStream_t stream) {
  const float* E = (const float*)d_in[0];
  const float* W1 = (const float*)d_in[1];
  const float* b1 = (const float*)d_in[2];
  const float* W2 = (const float*)d_in[3];
  const float* b2 = (const float*)d_in[4];
  float* out = (float*)d_out;

  const size_t need = (size_t)B_ * H_ * 2; // 512 KB bf16 embeddings
  if (ws_size >= need) {
    uint8_t* Ebf = (uint8_t*)d_ws;
    imec_prep<<<(B_ * H_ / 8) / 256, 256, 0, stream>>>(E, Ebf);
    imec_main<true><<<L_ / NL, 256, 0, stream>>>(E, W1, b1, W2, b2, out, Ebf);
  } else {
    imec_main<false><<<L_ / NL, 256, 0, stream>>>(E, W1, b1, W2, b2, out,
                                                  nullptr);
  }
}

// Round 2
// 493.038 us; speedup vs baseline: 1.0117x; 1.0117x over previous
//
#include <hip/hip_runtime.h>
#include <stdint.h>
#include <stddef.h>

// IMEC classifier: 10000 tiny MLPs (1024->8->1) over 256 embeddings.
//   logits[b,l] = sum_d relu( sum_h E[b,h]*W1[l,h,d] + b1[l,d] ) * W2[l,d] + b2[l]
// Strategy: bf16 MFMA (16x16x32), HBM-bound on the 328 MB W1 stream.
//   - prep kernel: E fp32 -> bf16 into d_ws, tiled+swizzled for global_load_lds
//   - main kernel: WG=256 thr, 8 labels, full 256-row batch.
//   R1 change: raw s_barrier + fine-grained vmcnt(8) keeps the 8 W1 prefetch
//   dwords in flight ACROSS the tile-ready barrier (no vmcnt(0) drain), fixing
//   the per-k-step ~900-cycle exposed HBM latency.

#define B_ 256
#define H_ 1024
#define L_ 10000
#define D_ 8
#define NL 8            // labels per workgroup
#define KB 32           // K elements per step
#define NSTEP (H_ / KB) // 32

typedef __bf16 bf16_t;
typedef bf16_t bf16x8 __attribute__((ext_vector_type(8)));
typedef float f32x4 __attribute__((ext_vector_type(4)));
typedef int i32x4 __attribute__((ext_vector_type(4)));

// round-to-nearest-even fp32 -> bf16, pack two into one dword
__device__ __forceinline__ uint32_t cvt_pk_bf16(float lo, float hi) {
  uint32_t a = __builtin_bit_cast(uint32_t, lo);
  uint32_t b = __builtin_bit_cast(uint32_t, hi);
  a += 0x7FFFu + ((a >> 16) & 1u);
  b += 0x7FFFu + ((b >> 16) & 1u);
  return (a >> 16) | (b & 0xFFFF0000u);
}

__device__ __forceinline__ void gl_lds16(const void* g, void* l) {
  __builtin_amdgcn_global_load_lds(
      (const __attribute__((address_space(1))) uint32_t*)g,
      (__attribute__((address_space(3))) uint32_t*)l, 16, 0, 0);
}

// Prep: E[256,1024] fp32 -> bf16 in d_ws, layout [kb 0..31][m 0..255][chunk 0..3][8 bf16]
// chunk swizzle: original chunk c stored at position c ^ ((m>>1)&3)  (A-read bank spread)
__global__ void imec_prep(const float* __restrict__ E, uint8_t* __restrict__ Ebf) {
  const int t = blockIdx.x * blockDim.x + threadIdx.x; // 0..32767
  const int m = t >> 7;       // row 0..255
  const int cg = t & 127;     // chunk-in-row 0..127
  const int kb = cg >> 2;     // k-step 0..31
  const int c = cg & 3;       // chunk within k-step
  const float* src = E + (size_t)m * H_ + kb * KB + c * 8;
  f32x4 x = *(const f32x4*)src;
  f32x4 y = *(const f32x4*)(src + 4);
  i32x4 v;
  v[0] = cvt_pk_bf16(x[0], x[1]);
  v[1] = cvt_pk_bf16(x[2], x[3]);
  v[2] = cvt_pk_bf16(y[0], y[1]);
  v[3] = cvt_pk_bf16(y[2], y[3]);
  const int cp = c ^ ((m >> 1) & 3);
  *(i32x4*)(Ebf + ((size_t)kb << 14) + (m << 6) + (cp << 4)) = v;
}

template <bool USE_WS>
__global__ __launch_bounds__(256, 2) void imec_main(
    const float* __restrict__ E, const float* __restrict__ W1,
    const float* __restrict__ b1, const float* __restrict__ W2,
    const float* __restrict__ b2, float* __restrict__ out,
    const uint8_t* __restrict__ Ebf) {
  // LDS: E tile [256 m][4 chunk][16B] = 16 KB ; W1 tile, MFMA-lane order:
  //      [pair 0..3][lane 0..63][16B] = 4 KB
  __shared__ alignas(16) uint8_t sE[16384];
  __shared__ alignas(16) uint8_t sW[4096];

  const int tid = threadIdx.x;
  const int w = tid >> 6;    // wave 0..3 (owns M rows [w*64, w*64+64), stages pair w)
  const int lane = tid & 63;
  const int wg = blockIdx.x; // labels [wg*8, wg*8+8)
  const int n = lane & 15;   // MFMA column / row-in-tile index
  const int q = lane >> 4;   // MFMA k-quad

  // --- W1 staging address for this lane (pair = w, its 16B B-frag chunk) ---
  const int d_st = n & 7;
  const int lp_st = n >> 3;
  const long label_st = (long)wg * NL + w * 2 + lp_st;
  const float* w1p = W1 + label_st * (long)(H_ * D_) + (q * 8) * D_ + d_st;

  f32x4 acc[4][4];
#pragma unroll
  for (int i = 0; i < 4; ++i)
#pragma unroll
    for (int j = 0; j < 4; ++j) acc[i][j] = (f32x4){0.f, 0.f, 0.f, 0.f};

  // prefetch k-step 0 W1 slab into regs (8 outstanding dword loads)
  float r[8];
#pragma unroll
  for (int j = 0; j < 8; ++j) r[j] = w1p[j * D_];
  w1p += KB * D_;

  const int sw = (n >> 1) & 3; // A-read chunk swizzle

  for (int kb = 0; kb < NSTEP; ++kb) {
    // ---- barrier (a): all waves done reading previous tile ----
    if constexpr (USE_WS) {
      asm volatile("s_barrier" ::: "memory");
    } else {
      __syncthreads();
    }

    // ---- stage E tile (4 DMA loads, OLDER than the W1 prefetch below) ----
    if constexpr (USE_WS) {
#pragma unroll
      for (int i = 0; i < 4; ++i) {
        const uint8_t* g =
            Ebf + ((size_t)kb << 14) + (w << 12) + (i << 10) + (lane << 4);
        gl_lds16(g, sE + (w << 12) + (i << 10)); // HW: +lane*16
      }
    } else {
      const int m = tid;
      const f32x4* er = (const f32x4*)(E + (size_t)m * H_ + kb * KB);
#pragma unroll
      for (int c = 0; c < 4; ++c) {
        f32x4 x = er[2 * c];
        f32x4 y = er[2 * c + 1];
        i32x4 v;
        v[0] = cvt_pk_bf16(x[0], x[1]);
        v[1] = cvt_pk_bf16(x[2], x[3]);
        v[2] = cvt_pk_bf16(y[0], y[1]);
        v[3] = cvt_pk_bf16(y[2], y[3]);
        *(i32x4*)(sE + (m << 6) + ((c ^ ((m >> 1) & 3)) << 4)) = v;
      }
    }

    // ---- stage W1 tile: cvt prefetched regs -> bf16, lane-ordered LDS ----
    // (compiler inserts the fine vmcnt wait for r[] here; the 4 E-DMAs stay
    //  outstanding or complete — either is fine)
    {
      i32x4 v;
      v[0] = cvt_pk_bf16(r[0], r[1]);
      v[1] = cvt_pk_bf16(r[2], r[3]);
      v[2] = cvt_pk_bf16(r[4], r[5]);
      v[3] = cvt_pk_bf16(r[6], r[7]);
      *(i32x4*)(sW + (w << 10) + (lane << 4)) = v;
    }

    if constexpr (USE_WS) {
      // pin ordering: E-DMAs (above) must stay older than W1 loads (below)
      __builtin_amdgcn_sched_barrier(0);
      if (kb + 1 < NSTEP) {
        // ---- issue next W1 slab (8 dword loads, NEWEST outstanding) ----
#pragma unroll
        for (int j = 0; j < 8; ++j) r[j] = w1p[j * D_];
        w1p += KB * D_;
        __builtin_amdgcn_sched_barrier(0);
        // barrier (b): wait E-DMAs (drain to 8 outstanding = the 8 W1 loads
        // stay IN FLIGHT across the barrier) + LDS writes visible.
        asm volatile("s_waitcnt vmcnt(8) lgkmcnt(0)\n\t"
                     "s_barrier" ::: "memory");
      } else {
        asm volatile("s_waitcnt vmcnt(0) lgkmcnt(0)\n\t"
                     "s_barrier" ::: "memory");
      }
    } else {
      __syncthreads();
      if (kb + 1 < NSTEP) {
#pragma unroll
        for (int j = 0; j < 8; ++j) r[j] = w1p[j * D_];
        w1p += KB * D_;
      }
    }

    // ---- fragments ----
    bf16x8 bfr[4];
#pragma unroll
    for (int t = 0; t < 4; ++t)
      bfr[t] = *(const bf16x8*)(sW + (t << 10) + (lane << 4));
    bf16x8 afr[4];
#pragma unroll
    for (int mt = 0; mt < 4; ++mt) {
      const int ml = w * 64 + mt * 16 + n;
      afr[mt] = *(const bf16x8*)(sE + (ml << 6) + ((q ^ sw) << 4));
    }

#pragma unroll
    for (int mt = 0; mt < 4; ++mt)
#pragma unroll
      for (int t = 0; t < 4; ++t)
        acc[mt][t] = __builtin_amdgcn_mfma_f32_16x16x32_bf16(
            afr[mt], bfr[t], acc[mt][t], 0, 0, 0);
  }

  // ---- epilogue: h -> relu(h+b1)*W2 summed over d (8 lanes), +b2 ----
  // C/D layout: col = lane&15 -> (pair-local label = n>>3, d = n&7),
  //             row = q*4 + reg -> batch row within tile.
#pragma unroll
  for (int t = 0; t < 4; ++t) {
    const int label = wg * NL + t * 2 + lp_st;
    const float b1v = b1[label * D_ + d_st];
    const float w2v = W2[label * D_ + d_st];
    const float b2v = b2[label];
#pragma unroll
    for (int mt = 0; mt < 4; ++mt) {
#pragma unroll
      for (int rr = 0; rr < 4; ++rr) {
        float v = acc[mt][t][rr] + b1v;
        v = fmaxf(v, 0.f) * w2v;
        v += __shfl_xor(v, 1);
        v += __shfl_xor(v, 2);
        v += __shfl_xor(v, 4);
        if ((lane & 7) == 0) { // n == 0 or 8 -> d == 0 lane of each label
          const int m = w * 64 + mt * 16 + q * 4 + rr;
          out[(size_t)m * L_ + label] = v + b2v;
        }
      }
    }
  }
}

extern "C" void kernel_launch(void* const* d_in, const int* in_sizes, int n_in,
                              void* d_out, int out_size, void* d_ws,
                              size_t ws_size, hipStream_t stream) {
  const float* E = (const float*)d_in[0];
  const float* W1 = (const float*)d_in[1];
  const float* b1 = (const float*)d_in[2];
  const float* W2 = (const float*)d_in[3];
  const float* b2 = (const float*)d_in[4];
  float* out = (float*)d_out;

  const size_t need = (size_t)B_ * H_ * 2; // 512 KB bf16 embeddings
  if (ws_size >= need) {
    uint8_t* Ebf = (uint8_t*)d_ws;
    imec_prep<<<(B_ * H_ / 8) / 256, 256, 0, stream>>>(E, Ebf);
    imec_main<true><<<L_ / NL, 256, 0, stream>>>(E, W1, b1, W2, b2, out, Ebf);
  } else {
    imec_main<false><<<L_ / NL, 256, 0, stream>>>(E, W1, b1, W2, b2, out,
                                                  nullptr);
  }
}

// Round 3
// 490.085 us; speedup vs baseline: 1.0178x; 1.0060x over previous
//
#include <hip/hip_runtime.h>
#include <stdint.h>
#include <stddef.h>

// IMEC classifier: 10000 tiny MLPs (1024->8->1) over 256 embeddings.
//   logits[b,l] = sum_d relu( sum_h E[b,h]*W1[l,h,d] + b1[l,d] ) * W2[l,d] + b2[l]
// bf16 MFMA 16x16x32; HBM-bound on the 328 MB W1 stream.
// R3: W1 loaded with coalesced dwordx4 (1 KB/label slab), d<->k transpose via
//     8x ds_write_b16 into lane-ordered sW; double-buffered sE DMA; barriers
//     never drain vmcnt to 0 in steady state (vmcnt(6) keeps next-step loads
//     in flight). Fixes the VMEM-issue bottleneck of the stride-32B loads.

#define B_ 256
#define H_ 1024
#define L_ 10000
#define D_ 8
#define NL 8            // labels per workgroup
#define KB 32           // K elements per step
#define NSTEP (H_ / KB) // 32

typedef __bf16 bf16_t;
typedef bf16_t bf16x8 __attribute__((ext_vector_type(8)));
typedef float f32x4 __attribute__((ext_vector_type(4)));
typedef int i32x4 __attribute__((ext_vector_type(4)));

__device__ __forceinline__ uint32_t cvt_pk_bf16(float lo, float hi) {
  uint32_t a = __builtin_bit_cast(uint32_t, lo);
  uint32_t b = __builtin_bit_cast(uint32_t, hi);
  a += 0x7FFFu + ((a >> 16) & 1u);
  b += 0x7FFFu + ((b >> 16) & 1u);
  return (a >> 16) | (b & 0xFFFF0000u);
}

__device__ __forceinline__ uint16_t cvt1_bf16(float x) {
  uint32_t a = __builtin_bit_cast(uint32_t, x);
  a += 0x7FFFu + ((a >> 16) & 1u);
  return (uint16_t)(a >> 16);
}

__device__ __forceinline__ void gl_lds16(const void* g, void* l) {
  __builtin_amdgcn_global_load_lds(
      (const __attribute__((address_space(1))) uint32_t*)g,
      (__attribute__((address_space(3))) uint32_t*)l, 16, 0, 0);
}

// Prep: E[256,1024] fp32 -> bf16 in d_ws, layout [kb 0..31][m 0..255][chunk 0..3][16B]
// chunk swizzle: chunk c stored at c ^ ((m>>1)&3)
__global__ void imec_prep(const float* __restrict__ E, uint8_t* __restrict__ Ebf) {
  const int t = blockIdx.x * blockDim.x + threadIdx.x; // 0..32767
  const int m = t >> 7;
  const int cg = t & 127;
  const int kb = cg >> 2;
  const int c = cg & 3;
  const float* src = E + (size_t)m * H_ + kb * KB + c * 8;
  f32x4 x = *(const f32x4*)src;
  f32x4 y = *(const f32x4*)(src + 4);
  i32x4 v;
  v[0] = cvt_pk_bf16(x[0], x[1]);
  v[1] = cvt_pk_bf16(x[2], x[3]);
  v[2] = cvt_pk_bf16(y[0], y[1]);
  v[3] = cvt_pk_bf16(y[2], y[3]);
  const int cp = c ^ ((m >> 1) & 3);
  *(i32x4*)(Ebf + ((size_t)kb << 14) + (m << 6) + (cp << 4)) = v;
}

template <bool USE_WS>
__global__ __launch_bounds__(256, 2) void imec_main(
    const float* __restrict__ E, const float* __restrict__ W1,
    const float* __restrict__ b1, const float* __restrict__ W2,
    const float* __restrict__ b2, float* __restrict__ out,
    const uint8_t* __restrict__ Ebf) {
  // sE: 2 buffers x [w][i][lane*16B] = 2 x 16 KB (double-buffered DMA dest)
  // sW: [pair t][q][n][8 bf16] = 4 KB, single buffer (2-barrier protected)
  __shared__ alignas(16) uint8_t sE[32768];
  __shared__ alignas(16) uint8_t sW[4096];

  const int tid = threadIdx.x;
  const int w = tid >> 6;    // wave: owns M rows [w*64,..), stages label pair w
  const int lane = tid & 63;
  const int wg = blockIdx.x; // labels [wg*8, wg*8+8)
  const int n = lane & 15;   // MFMA col / A-row index
  const int q = lane >> 4;   // MFMA k-quad

  // W1 coalesced staging: wave w loads labels lab0=wg*8+w*2, lab1=lab0+1.
  // Lane takes 16 B of the 1 KB k-step slab: holds (row r=lane>>1, d-quad dq=lane&1).
  const int lab0 = wg * NL + w * 2;
  const float* p0 = W1 + (size_t)lab0 * (H_ * D_) + lane * 4;
  const float* p1 = p0 + (H_ * D_);

  // ds_write_b16 base (halfword units): w*512 + (r>>3)*128 + dq*32 + (r&7)
  const int rrow = lane >> 1;
  const int dq = lane & 1;
  const int wbase = (w << 9) + ((rrow >> 3) << 7) + (dq << 5) + (rrow & 7);
  uint16_t* sW16 = (uint16_t*)sW;

  f32x4 acc[4][4];
#pragma unroll
  for (int i = 0; i < 4; ++i)
#pragma unroll
    for (int j = 0; j < 4; ++j) acc[i][j] = (f32x4){0.f, 0.f, 0.f, 0.f};

  const int sw = (n >> 1) & 3; // sE chunk swizzle for A reads

  f32x4 r0, r1, rn0, rn1;

  // ---- preamble: issue step-0 E DMA (into sE[0]) and W1 loads ----
  if constexpr (USE_WS) {
#pragma unroll
    for (int i = 0; i < 4; ++i) {
      const uint8_t* g = Ebf + (w << 12) + (i << 10) + (lane << 4);
      gl_lds16(g, sE + (w << 12) + (i << 10));
    }
    __builtin_amdgcn_sched_barrier(0);
  }
  r0 = *(const f32x4*)p0;
  r1 = *(const f32x4*)p1;
  if constexpr (USE_WS) __builtin_amdgcn_sched_barrier(0);

  for (int kb = 0; kb < NSTEP; ++kb) {
    const int eb = kb & 1;

    if constexpr (USE_WS) {
      // barrier (a): all waves done reading sW / sE[1-eb] from prior steps
      asm volatile("s_barrier" ::: "memory");
      if (kb + 1 < NSTEP) {
        // E DMA for step kb+1 into sE[1-eb] (4 insts, oldest of this iter)
#pragma unroll
        for (int i = 0; i < 4; ++i) {
          const uint8_t* g = Ebf + (((size_t)(kb + 1)) << 14) + (w << 12) +
                             (i << 10) + (lane << 4);
          gl_lds16(g, sE + ((1 - eb) << 14) + (w << 12) + (i << 10));
        }
        __builtin_amdgcn_sched_barrier(0);
        // W1 loads for step kb+1 (2 insts, newest)
        rn0 = *(const f32x4*)(p0 + (size_t)(kb + 1) * (KB * D_));
        rn1 = *(const f32x4*)(p1 + (size_t)(kb + 1) * (KB * D_));
        __builtin_amdgcn_sched_barrier(0);
      }
    } else {
      __syncthreads();
      // stage E tile directly from fp32 E
      const int m = tid;
      const f32x4* er = (const f32x4*)(E + (size_t)m * H_ + kb * KB);
#pragma unroll
      for (int c = 0; c < 4; ++c) {
        f32x4 x = er[2 * c];
        f32x4 y = er[2 * c + 1];
        i32x4 v;
        v[0] = cvt_pk_bf16(x[0], x[1]);
        v[1] = cvt_pk_bf16(x[2], x[3]);
        v[2] = cvt_pk_bf16(y[0], y[1]);
        v[3] = cvt_pk_bf16(y[2], y[3]);
        *(i32x4*)(sE + (m << 6) + ((c ^ ((m >> 1) & 3)) << 4)) = v;
      }
      if (kb + 1 < NSTEP) {
        rn0 = *(const f32x4*)(p0 + (size_t)(kb + 1) * (KB * D_));
        rn1 = *(const f32x4*)(p1 + (size_t)(kb + 1) * (KB * D_));
      }
    }

    // ---- transpose-store W1 regs (compiler waits vmcnt for r0/r1 here;
    //      that wait also drains the older E-DMAs of step kb) ----
    // element (r, d=dq*4+i) of label lab0+lp -> sW16[w*512 + (r>>3)*128 +
    //   (lp*8+d)*8 + (r&7)]
#pragma unroll
    for (int i = 0; i < 4; ++i) sW16[wbase + i * 8] = cvt1_bf16(r0[i]);
#pragma unroll
    for (int i = 0; i < 4; ++i) sW16[wbase + 64 + i * 8] = cvt1_bf16(r1[i]);

    if constexpr (USE_WS) {
      if (kb + 1 < NSTEP)
        // barrier (b): LDS writes visible; the 6 step-(kb+1) loads STAY in
        // flight across the barrier (vmcnt(6)), older ops (E DMA kb) drained.
        asm volatile("s_waitcnt vmcnt(6) lgkmcnt(0)\n\t"
                     "s_barrier" ::: "memory");
      else
        asm volatile("s_waitcnt vmcnt(0) lgkmcnt(0)\n\t"
                     "s_barrier" ::: "memory");
    } else {
      __syncthreads();
    }

    // ---- fragments ----
    const uint8_t* sEb = sE + (USE_WS ? (eb << 14) : 0);
    bf16x8 bfr[4];
#pragma unroll
    for (int t = 0; t < 4; ++t)
      bfr[t] = *(const bf16x8*)(sW + (t << 10) + (lane << 4));
    bf16x8 afr[4];
#pragma unroll
    for (int mt = 0; mt < 4; ++mt) {
      const int ml = w * 64 + mt * 16 + n;
      afr[mt] = *(const bf16x8*)(sEb + (ml << 6) + ((q ^ sw) << 4));
    }

#pragma unroll
    for (int mt = 0; mt < 4; ++mt)
#pragma unroll
      for (int t = 0; t < 4; ++t)
        acc[mt][t] = __builtin_amdgcn_mfma_f32_16x16x32_bf16(
            afr[mt], bfr[t], acc[mt][t], 0, 0, 0);

    if (kb + 1 < NSTEP) {
      r0 = rn0;
      r1 = rn1;
    }
  }

  // ---- epilogue: relu(h+b1)*W2 summed over d (8 lanes), +b2 ----
  // C/D: col = lane&15 -> (lp = n>>3, d = n&7); row = q*4 + reg.
  const int d_st = n & 7;
  const int lp_st = n >> 3;
#pragma unroll
  for (int t = 0; t < 4; ++t) {
    const int label = wg * NL + t * 2 + lp_st;
    const float b1v = b1[label * D_ + d_st];
    const float w2v = W2[label * D_ + d_st];
    const float b2v = b2[label];
#pragma unroll
    for (int mt = 0; mt < 4; ++mt) {
#pragma unroll
      for (int rr = 0; rr < 4; ++rr) {
        float v = acc[mt][t][rr] + b1v;
        v = fmaxf(v, 0.f) * w2v;
        v += __shfl_xor(v, 1);
        v += __shfl_xor(v, 2);
        v += __shfl_xor(v, 4);
        if ((lane & 7) == 0) {
          const int m = w * 64 + mt * 16 + q * 4 + rr;
          out[(size_t)m * L_ + label] = v + b2v;
        }
      }
    }
  }
}

extern "C" void kernel_launch(void* const* d_in, const int* in_sizes, int n_in,
                              void* d_out, int out_size, void* d_ws,
                              size_t ws_size, hipStream_t stream) {
  const float* E = (const float*)d_in[0];
  const float* W1 = (const float*)d_in[1];
  const float* b1 = (const float*)d_in[2];
  const float* W2 = (const float*)d_in[3];
  const float* b2 = (const float*)d_in[4];
  float* out = (float*)d_out;

  const size_t need = (size_t)B_ * H_ * 2; // 512 KB bf16 embeddings
  if (ws_size >= need) {
    uint8_t* Ebf = (uint8_t*)d_ws;
    imec_prep<<<(B_ * H_ / 8) / 256, 256, 0, stream>>>(E, Ebf);
    imec_main<true><<<L_ / NL, 256, 0, stream>>>(E, W1, b1, W2, b2, out, Ebf);
  } else {
    imec_main<false><<<L_ / NL, 256, 0, stream>>>(E, W1, b1, W2, b2, out,
                                                  nullptr);
  }
}